// Round 1
// baseline (659.131 us; speedup 1.0000x reference)
//
#include <hip/hip_runtime.h>

#define INV_SQRT2 0.70710678118654752440f

// Phase 1: h[row][o] = (x[row] . W[o]) * 1/sqrt(2)  for W in {Wsrc, Wdst}
// One thread per node-row; blockIdx.y selects which weight matrix.
// x row lives in 64 VGPRs; W accessed with wave-uniform indices so the
// compiler can emit scalar (s_load) reads from constant cache.
__global__ __launch_bounds__(256) void transform_k(
    const float* __restrict__ x,
    const float* __restrict__ Wsrc,
    const float* __restrict__ Wdst,
    float* __restrict__ hs,
    float* __restrict__ hd,
    int total_rows)
{
    int row = blockIdx.x * blockDim.x + threadIdx.x;
    if (row >= total_rows) return;

    const float* __restrict__ W = (blockIdx.y == 0) ? Wsrc : Wdst;
    float* __restrict__ h = (blockIdx.y == 0) ? hs : hd;

    // Load x row (64 floats) into registers via 16x float4.
    float xr[64];
    const float4* xp = reinterpret_cast<const float4*>(x + (size_t)row * 64);
#pragma unroll
    for (int i = 0; i < 16; ++i) {
        float4 v = xp[i];
        xr[4 * i + 0] = v.x;
        xr[4 * i + 1] = v.y;
        xr[4 * i + 2] = v.z;
        xr[4 * i + 3] = v.w;
    }

    float* __restrict__ hrow = h + (size_t)row * 64;
#pragma unroll 2
    for (int o = 0; o < 64; ++o) {
        const float* __restrict__ wr = W + o * 64;  // uniform address -> s_load
        float acc = 0.0f;
#pragma unroll
        for (int k = 0; k < 64; ++k) acc = fmaf(xr[k], wr[k], acc);
        hrow[o] = acc * INV_SQRT2;
    }
}

// Phase 2: out[b][e][:] = hs[b][src[e]][:] + hd[b][dst[e]][:]
// (scale already folded into hs/hd). One thread per float4 of output.
// Lanes 16t..16t+15 cover one row -> stores are fully coalesced; the two
// gathered rows are 256B contiguous chunks resident in L2/L3.
__global__ __launch_bounds__(256) void gather_k(
    const float4* __restrict__ hs,
    const float4* __restrict__ hd,
    const int* __restrict__ src,
    const int* __restrict__ dst,
    float4* __restrict__ out,
    int E, int N)
{
    int t = blockIdx.x * 256 + threadIdx.x;  // [0, E*16)
    if (t >= E * 16) return;
    int e = t >> 4;
    int c = t & 15;
    int b = blockIdx.y;

    int s = src[e];
    int d = dst[e];

    float4 a = hs[((size_t)b * N + s) * 16 + c];
    float4 g = hd[((size_t)b * N + d) * 16 + c];

    float4 o4;
    o4.x = a.x + g.x;
    o4.y = a.y + g.y;
    o4.z = a.z + g.z;
    o4.w = a.w + g.w;
    out[((size_t)b * E + e) * 16 + c] = o4;
}

// Safety net if workspace is too small for hs/hd (51.2 MB): fused per-edge
// compute. Correct but redundant (16x more FLOPs); only used if ws_size is
// insufficient, which is a constant property of the session (graph-safe).
__global__ __launch_bounds__(256) void fused_fallback_k(
    const float* __restrict__ x,
    const int* __restrict__ src,
    const int* __restrict__ dst,
    const float* __restrict__ Wsrc,
    const float* __restrict__ Wdst,
    float* __restrict__ out,
    int E, int N)
{
    int t = blockIdx.x * 256 + threadIdx.x;  // [0, E*64)
    if (t >= E * 64) return;
    int o = t & 63;
    int e = t >> 6;
    int b = blockIdx.y;

    const float* xs = x + ((size_t)b * N + src[e]) * 64;
    const float* xd = x + ((size_t)b * N + dst[e]) * 64;
    const float* ws = Wsrc + o * 64;
    const float* wd = Wdst + o * 64;
    float acc = 0.0f;
#pragma unroll
    for (int k = 0; k < 64; ++k) {
        acc = fmaf(xs[k], ws[k], acc);
        acc = fmaf(xd[k], wd[k], acc);
    }
    out[((size_t)b * E + e) * 64 + o] = acc * INV_SQRT2;
}

extern "C" void kernel_launch(void* const* d_in, const int* in_sizes, int n_in,
                              void* d_out, int out_size, void* d_ws, size_t ws_size,
                              hipStream_t stream)
{
    const float* x    = (const float*)d_in[0];
    const int*   src  = (const int*)d_in[1];
    const int*   dst  = (const int*)d_in[2];
    const float* Wsrc = (const float*)d_in[3];
    const float* Wdst = (const float*)d_in[4];
    float* out = (float*)d_out;

    const int E = in_sizes[1];
    const long long xsz = in_sizes[0];
    const int B = (int)((long long)out_size / ((long long)E * 64));  // = 2
    const int N = (int)(xsz / ((long long)B * 64));                  // = 50000
    const int rows = B * N;                                          // = 100000

    const size_t need = (size_t)2 * (size_t)rows * 64 * sizeof(float);  // 51.2 MB

    if (ws_size >= need) {
        float* hs = (float*)d_ws;
        float* hd = hs + (size_t)rows * 64;

        dim3 g1((rows + 255) / 256, 2);
        transform_k<<<g1, 256, 0, stream>>>(x, Wsrc, Wdst, hs, hd, rows);

        dim3 g2((E * 16 + 255) / 256, B);
        gather_k<<<g2, 256, 0, stream>>>((const float4*)hs, (const float4*)hd,
                                         src, dst, (float4*)out, E, N);
    } else {
        dim3 g((E * 64 + 255) / 256, B);
        fused_fallback_k<<<g, 256, 0, stream>>>(x, src, dst, Wsrc, Wdst, out, E, N);
    }
}

// Round 2
// 504.865 us; speedup vs baseline: 1.3056x; 1.3056x over previous
//
#include <hip/hip_runtime.h>

#define INV_SQRT2 0.70710678118654752440f

typedef __attribute__((ext_vector_type(8))) short bf16x8;   // 8 bf16 = 4 VGPRs (MFMA A/B frag)
typedef __attribute__((ext_vector_type(4))) float f32x4;    // MFMA C/D frag

__device__ __forceinline__ unsigned short f32_to_bf16_rne(float f) {
    unsigned int u = __builtin_bit_cast(unsigned int, f);
    u += 0x7FFFu + ((u >> 16) & 1u);       // round-to-nearest-even
    return (unsigned short)(u >> 16);
}
__device__ __forceinline__ float bf16_to_f32(unsigned short h) {
    return __builtin_bit_cast(float, ((unsigned int)h) << 16);
}

// ---------------------------------------------------------------------------
// Phase 0: convert [x | Wsrc | Wdst] fp32 -> bf16 into [xb | Wb].
// 8 elems/thread, 32B fp32 in, 16B bf16 out. ~38 MB traffic total -> ~6 us.
// ---------------------------------------------------------------------------
__global__ __launch_bounds__(256) void convert_k(
    const float* __restrict__ x,
    const float* __restrict__ Wsrc,
    const float* __restrict__ Wdst,
    unsigned short* __restrict__ xb,
    unsigned short* __restrict__ Wb,
    long long nx, int nw)   // nx = rows*64 (mult of 8), nw = 64*64
{
    long long t = (long long)blockIdx.x * 256 + threadIdx.x;
    long long total8 = (nx + 2LL * nw) >> 3;
    if (t >= total8) return;
    long long base = t << 3;

    const float* sp;
    unsigned short* dp;
    if (base < nx)            { sp = x    + base;            dp = xb + base; }
    else if (base < nx + nw)  { sp = Wsrc + (base - nx);      dp = Wb + (base - nx); }
    else                      { sp = Wdst + (base - nx - nw); dp = Wb + (base - nx); }

    float4 a = ((const float4*)sp)[0];
    float4 b = ((const float4*)sp)[1];
    uint4 o;
    o.x = (unsigned)f32_to_bf16_rne(a.x) | ((unsigned)f32_to_bf16_rne(a.y) << 16);
    o.y = (unsigned)f32_to_bf16_rne(a.z) | ((unsigned)f32_to_bf16_rne(a.w) << 16);
    o.z = (unsigned)f32_to_bf16_rne(b.x) | ((unsigned)f32_to_bf16_rne(b.y) << 16);
    o.w = (unsigned)f32_to_bf16_rne(b.z) | ((unsigned)f32_to_bf16_rne(b.w) << 16);
    *((uint4*)dp) = o;
}

// ---------------------------------------------------------------------------
// Phase 1: h[row][0:128] = (x[row] . W[n]) * INV_SQRT2 via bf16 MFMA.
// GEMM M=rows, N=128 (Wsrc|Wdst), K=64. One wave per 16-row tile; wave does
// all 8 col-tiles (A frags loaded once). Fragments load directly from
// row-major bf16: A[m=lane&15][k=quad*8+j], B[k=quad*8+j][n=lane&15]=W[n][k].
// ---------------------------------------------------------------------------
__global__ __launch_bounds__(256) void transform_mfma_k(
    const unsigned short* __restrict__ xb,   // (rows, 64) bf16
    const unsigned short* __restrict__ Wb,   // (128, 64) bf16  [Wsrc;Wdst]
    unsigned short* __restrict__ hb,         // (rows, 128) bf16
    int rows)
{
    int wave = (blockIdx.x * 256 + threadIdx.x) >> 6;
    int lane = threadIdx.x & 63;
    int row_tiles = (rows + 15) >> 4;
    if (wave >= row_tiles) return;

    int m    = lane & 15;
    int quad = lane >> 4;

    int arow_i = wave * 16 + m;
    if (arow_i >= rows) arow_i = rows - 1;          // clamp load (store is guarded)
    const bf16x8* arow = (const bf16x8*)(xb + (size_t)arow_i * 64);
    bf16x8 a0 = arow[quad];        // k = quad*8 + j,      k in [0,32)
    bf16x8 a1 = arow[4 + quad];    // k = 32 + quad*8 + j, k in [32,64)

    f32x4 acc[8];
#pragma unroll
    for (int ct = 0; ct < 8; ++ct) {
        int n = ct * 16 + m;
        const bf16x8* brow = (const bf16x8*)(Wb + (size_t)n * 64);
        bf16x8 b0 = brow[quad];
        bf16x8 b1 = brow[4 + quad];
        f32x4 c = {0.f, 0.f, 0.f, 0.f};
        c = __builtin_amdgcn_mfma_f32_16x16x32_bf16(a0, b0, c, 0, 0, 0);
        c = __builtin_amdgcn_mfma_f32_16x16x32_bf16(a1, b1, c, 0, 0, 0);
        acc[ct] = c;
    }

    // C/D layout: col = lane&15, row = quad*4 + r
#pragma unroll
    for (int ct = 0; ct < 8; ++ct) {
#pragma unroll
        for (int r = 0; r < 4; ++r) {
            int orow = wave * 16 + quad * 4 + r;
            if (orow < rows) {
                hb[(size_t)orow * 128 + ct * 16 + m] =
                    f32_to_bf16_rne(acc[ct][r] * INV_SQRT2);
            }
        }
    }
}

// ---------------------------------------------------------------------------
// Phase 2: out[b][e][:] = hs_row + hd_row (scale pre-folded). 16 lanes/edge;
// 8B bf16 loads from L2/L3-resident hb (25.6 MB), perfectly coalesced float4
// stores (the HBM-write floor gets the ideal pattern).
// ---------------------------------------------------------------------------
__global__ __launch_bounds__(256) void gather_k(
    const unsigned short* __restrict__ hb,   // (B*N, 128) bf16
    const int* __restrict__ src,
    const int* __restrict__ dst,
    float4* __restrict__ out,
    int E, int N)
{
    int t = blockIdx.x * 256 + threadIdx.x;  // [0, E*16)
    if (t >= E * 16) return;
    int e = t >> 4;
    int c = t & 15;
    int b = blockIdx.y;

    int s = src[e];
    int d = dst[e];

    const unsigned short* ps = hb + ((size_t)(b * N + s)) * 128 + c * 4;
    const unsigned short* pd = hb + ((size_t)(b * N + d)) * 128 + 64 + c * 4;
    ushort4 us = *(const ushort4*)ps;
    ushort4 ud = *(const ushort4*)pd;

    float4 o;
    o.x = bf16_to_f32(us.x) + bf16_to_f32(ud.x);
    o.y = bf16_to_f32(us.y) + bf16_to_f32(ud.y);
    o.z = bf16_to_f32(us.z) + bf16_to_f32(ud.z);
    o.w = bf16_to_f32(us.w) + bf16_to_f32(ud.w);

    out[((size_t)b * E + e) * 16 + c] = o;
}

// ---------------------------------------------------------------------------
// Fallback (ws too small): fused per-edge fp32 compute. Correct, slow.
// ---------------------------------------------------------------------------
__global__ __launch_bounds__(256) void fused_fallback_k(
    const float* __restrict__ x,
    const int* __restrict__ src,
    const int* __restrict__ dst,
    const float* __restrict__ Wsrc,
    const float* __restrict__ Wdst,
    float* __restrict__ out,
    int E, int N)
{
    int t = blockIdx.x * 256 + threadIdx.x;
    if (t >= E * 64) return;
    int o = t & 63;
    int e = t >> 6;
    int b = blockIdx.y;

    const float* xs = x + ((size_t)(b * N + src[e])) * 64;
    const float* xd = x + ((size_t)(b * N + dst[e])) * 64;
    const float* ws = Wsrc + o * 64;
    const float* wd = Wdst + o * 64;
    float acc = 0.0f;
#pragma unroll
    for (int k = 0; k < 64; ++k) {
        acc = fmaf(xs[k], ws[k], acc);
        acc = fmaf(xd[k], wd[k], acc);
    }
    out[((size_t)b * E + e) * 64 + o] = acc * INV_SQRT2;
}

extern "C" void kernel_launch(void* const* d_in, const int* in_sizes, int n_in,
                              void* d_out, int out_size, void* d_ws, size_t ws_size,
                              hipStream_t stream)
{
    const float* x    = (const float*)d_in[0];
    const int*   src  = (const int*)d_in[1];
    const int*   dst  = (const int*)d_in[2];
    const float* Wsrc = (const float*)d_in[3];
    const float* Wdst = (const float*)d_in[4];
    float* out = (float*)d_out;

    const int E = in_sizes[1];
    const long long xsz = in_sizes[0];
    const int B = (int)((long long)out_size / ((long long)E * 64));  // 2
    const int N = (int)(xsz / ((long long)B * 64));                  // 50000
    const int rows = B * N;                                          // 100000

    // ws layout: xb (rows*64 bf16) | Wb (128*64 bf16) | hb (rows*128 bf16)
    const size_t xb_elems = (size_t)rows * 64;
    const size_t wb_elems = 128 * 64;
    const size_t hb_elems = (size_t)rows * 128;
    const size_t need = (xb_elems + wb_elems + hb_elems) * sizeof(unsigned short);

    if (ws_size >= need) {
        unsigned short* xb = (unsigned short*)d_ws;
        unsigned short* Wb = xb + xb_elems;
        unsigned short* hb = Wb + wb_elems;

        long long nx = (long long)rows * 64;
        int nw = 64 * 64;
        long long total8 = (nx + 2LL * nw) >> 3;
        int g0 = (int)((total8 + 255) / 256);
        convert_k<<<g0, 256, 0, stream>>>(x, Wsrc, Wdst, xb, Wb, nx, nw);

        int row_tiles = (rows + 15) >> 4;            // waves needed
        int g1 = (row_tiles + 3) / 4;                // 4 waves/block
        transform_mfma_k<<<g1, 256, 0, stream>>>(xb, Wb, hb, rows);

        dim3 g2((E * 16 + 255) / 256, B);
        gather_k<<<g2, 256, 0, stream>>>(hb, src, dst, (float4*)out, E, N);
    } else {
        dim3 g((E * 64 + 255) / 256, B);
        fused_fallback_k<<<g, 256, 0, stream>>>(x, src, dst, Wsrc, Wdst, out, E, N);
    }
}